// Round 3
// baseline (353.908 us; speedup 1.0000x reference)
//
#include <hip/hip_runtime.h>
#include <math.h>

#define B_ 64
#define F_ 512   // feature dim = GEMM K
#define T_ 600
#define M_ 200   // merge_size = GEMM M and N

// Merged layout: (B, F, M) row-major  ->  dst[b*F*M + f*M + m]
// This gives coalesced merge writes AND K-major coalesced GEMM tile loads.

__global__ __launch_bounds__(256)
void merge_kernel(const float* __restrict__ a,
                  const float* __restrict__ b,
                  float* __restrict__ fa,
                  float* __restrict__ fb) {
    const float* src = (blockIdx.y == 0) ? a : b;
    float*       dst = (blockIdx.y == 0) ? fa : fb;
    int idx = blockIdx.x * 256 + threadIdx.x;      // = b*F*M + f*M + m
    int m  = idx % M_;
    int bf = idx / M_;                             // = b*F + f
    const float* s = src + (size_t)bf * T_;
    float v;
    if (m < M_ - 1) {
        int t = 3 * m + 1;
        v = s[t] + s[t + 1] + s[t + 2];
    } else {
        // segment 199 collects t in {0, 598, 599}
        v = s[0] + s[598] + s[599];
    }
    dst[idx] = v;
}

__global__ __launch_bounds__(256)
void norm_kernel(const float* __restrict__ fa, const float* __restrict__ fb,
                 float* __restrict__ na, float* __restrict__ nb) {
    int b = blockIdx.x;
    const float* src = (blockIdx.y == 0) ? fa : fb;
    float*       dst = (blockIdx.y == 0) ? na : nb;
    int m = threadIdx.x;
    if (m >= M_) return;
    const float* p = src + (size_t)b * F_ * M_ + m;
    float acc = 0.f;
    #pragma unroll 8
    for (int f = 0; f < F_; ++f) {
        float v = p[(size_t)f * M_];
        acc = fmaf(v, v, acc);
    }
    dst[b * M_ + m] = sqrtf(acc);
}

#define BM 64
#define BN 64
#define BK 32

// C[b,m,n] = sum_f A[b,f,m] * B[b,f,n]   (both operands K-major)
__global__ __launch_bounds__(256)
void gemm_kernel(const float* __restrict__ fa, const float* __restrict__ fb,
                 float* __restrict__ num) {
    __shared__ __align__(16) float As[BK][BM];
    __shared__ __align__(16) float Bs[BK][BN];
    int b  = blockIdx.z;
    int m0 = blockIdx.x * BM;
    int n0 = blockIdx.y * BN;
    const float* A = fa + (size_t)b * F_ * M_;
    const float* B = fb + (size_t)b * F_ * M_;
    int tid = threadIdx.x;
    int tx = tid & 15;          // -> m group (4 consecutive m)
    int ty = tid >> 4;          // -> n group (4 consecutive n)

    float acc[4][4];
    #pragma unroll
    for (int i = 0; i < 4; ++i)
        #pragma unroll
        for (int j = 0; j < 4; ++j) acc[i][j] = 0.f;

    for (int k0 = 0; k0 < F_; k0 += BK) {
        // 2048 elements per operand, 8 per thread, coalesced rows of 64
        #pragma unroll
        for (int i = 0; i < BK * BM / 256; ++i) {
            int e  = tid + i * 256;
            int kk = e >> 6;
            int mm = e & 63;
            int gm = m0 + mm;
            int gn = n0 + mm;
            size_t rowoff = (size_t)(k0 + kk) * M_;
            As[kk][mm] = (gm < M_) ? A[rowoff + gm] : 0.f;
            Bs[kk][mm] = (gn < M_) ? B[rowoff + gn] : 0.f;
        }
        __syncthreads();
        #pragma unroll
        for (int kk = 0; kk < BK; ++kk) {
            float a4[4], b4[4];
            *(float4*)a4 = *(const float4*)&As[kk][tx * 4];
            *(float4*)b4 = *(const float4*)&Bs[kk][ty * 4];
            #pragma unroll
            for (int i = 0; i < 4; ++i)
                #pragma unroll
                for (int j = 0; j < 4; ++j)
                    acc[i][j] = fmaf(a4[i], b4[j], acc[i][j]);
        }
        __syncthreads();
    }
    float* C = num + (size_t)b * M_ * M_;
    #pragma unroll
    for (int i = 0; i < 4; ++i) {
        int m = m0 + tx * 4 + i;
        if (m >= M_) continue;
        #pragma unroll
        for (int j = 0; j < 4; ++j) {
            int n = n0 + ty * 4 + j;
            if (n < M_) C[(size_t)m * M_ + n] = acc[i][j];
        }
    }
}

// one 64-lane wave per (b, m) row
__global__ __launch_bounds__(64)
void row_softmax_kernel(const float* __restrict__ num,
                        const float* __restrict__ na,
                        const float* __restrict__ nb,
                        float* __restrict__ partial) {
    int bm = blockIdx.x;           // b*M + m
    int b  = bm / M_;
    int m  = bm - b * M_;
    int lane = threadIdx.x;
    const float* row = num + (size_t)b * M_ * M_ + (size_t)m * M_;
    const float* nbp = nb + b * M_;
    float nam = na[bm];

    float cosv[4];
    float mx = -INFINITY;
    #pragma unroll
    for (int r = 0; r < 4; ++r) {
        int n = lane + r * 64;
        float c = -INFINITY;
        if (n < M_) {
            float denom = fmaxf(nam * nbp[n], 1e-8f);
            c = row[n] / denom;
        }
        cosv[r] = c;
        mx = fmaxf(mx, c);
    }
    #pragma unroll
    for (int off = 32; off >= 1; off >>= 1)
        mx = fmaxf(mx, __shfl_xor(mx, off, 64));

    float s = 0.f, diag = 0.f;
    #pragma unroll
    for (int r = 0; r < 4; ++r) {
        int n = lane + r * 64;
        if (n < M_) {
            s += __expf(cosv[r] - mx);
            if (n == m) diag = cosv[r];
        }
    }
    #pragma unroll
    for (int off = 32; off >= 1; off >>= 1) {
        s    += __shfl_xor(s, off, 64);
        diag += __shfl_xor(diag, off, 64);
    }
    if (lane == 0) {
        float lse = mx + __logf(s);
        partial[bm] = -(diag - lse) / (float)M_;
    }
}

__global__ __launch_bounds__(256)
void final_reduce_kernel(const float* __restrict__ partial, float* __restrict__ out, int n) {
    __shared__ float sm[256];
    float acc = 0.f;
    for (int i = threadIdx.x; i < n; i += 256) acc += partial[i];
    sm[threadIdx.x] = acc;
    __syncthreads();
    #pragma unroll
    for (int st = 128; st > 0; st >>= 1) {
        if (threadIdx.x < st) sm[threadIdx.x] += sm[threadIdx.x + st];
        __syncthreads();
    }
    if (threadIdx.x == 0) out[0] = sm[0];
}

extern "C" void kernel_launch(void* const* d_in, const int* in_sizes, int n_in,
                              void* d_out, int out_size, void* d_ws, size_t ws_size,
                              hipStream_t stream) {
    // d_in[0] = data_label (int64) -- unused by the loss
    const float* a_in = (const float*)d_in[1];
    const float* b_in = (const float*)d_in[2];

    float* ws = (float*)d_ws;
    const size_t merged_elems = (size_t)B_ * F_ * M_;     // 6,553,600
    float* fa      = ws;
    float* fb      = fa + merged_elems;
    float* num     = fb + merged_elems;                   // B*M*M = 2,560,000
    float* na      = num + (size_t)B_ * M_ * M_;
    float* nb      = na + B_ * M_;
    float* partial = nb + B_ * M_;                        // B*M = 12,800

    // 1. merge (B,F,T) -> (B,F,M)
    merge_kernel<<<dim3((unsigned)(merged_elems / 256), 2), 256, 0, stream>>>(a_in, b_in, fa, fb);
    // 2. per-row L2 norms
    norm_kernel<<<dim3(B_, 2), 256, 0, stream>>>(fa, fb, na, nb);
    // 3. batched GEMM num[b,m,n]
    gemm_kernel<<<dim3((M_ + BM - 1) / BM, (M_ + BN - 1) / BN, B_), 256, 0, stream>>>(fa, fb, num);
    // 4. cosine + log-softmax diag per row
    row_softmax_kernel<<<dim3(B_ * M_), 64, 0, stream>>>(num, na, nb, partial);
    // 5. total loss
    final_reduce_kernel<<<1, 256, 0, stream>>>(partial, (float*)d_out, B_ * M_);
}

// Round 7
// 256.503 us; speedup vs baseline: 1.3797x; 1.3797x over previous
//
#include <hip/hip_runtime.h>
#include <hip/hip_bf16.h>
#include <math.h>

#define B_ 64
#define F_ 512   // feature dim = GEMM K
#define T_ 600
#define M_ 200   // merge_size = GEMM M and N

typedef __attribute__((ext_vector_type(8))) short bf16x8_t;  // 8 bf16 = 4 VGPRs (MFMA A/B frag)
typedef __attribute__((ext_vector_type(4))) float f32x4_t;   // MFMA C/D frag

static __device__ __forceinline__ unsigned short f2bf(float v) {
    __hip_bfloat16 h = __float2bfloat16(v);
    return *reinterpret_cast<unsigned short*>(&h);
}
static __device__ __forceinline__ float bf2f(unsigned short u) {
    return __uint_as_float(((unsigned)u) << 16);
}

// ---------------------------------------------------------------------------
// Merge (B,F,T) fp32  ->  (B,M,F) bf16  (transposed via LDS tile)
// grid: (B_ * F_/32, 2), block 256.  Each block: one b, 32 f-rows, all 200 m.
// ---------------------------------------------------------------------------
__global__ __launch_bounds__(256)
void merge_t_kernel(const float* __restrict__ a, const float* __restrict__ b,
                    unsigned short* __restrict__ fa, unsigned short* __restrict__ fb) {
    const float* src = (blockIdx.y == 0) ? a : b;
    unsigned short* dst = (blockIdx.y == 0) ? fa : fb;
    int blk = blockIdx.x;
    int bb  = blk >> 4;            // / (F_/32 = 16)
    int f0  = (blk & 15) * 32;

    __shared__ unsigned short tile[32][204];   // [f][m], padded

    int t = threadIdx.x;
    // 32 f * 200 m = 6400 merged elements; 25 per thread
    #pragma unroll
    for (int i = 0; i < 25; ++i) {
        int e = t + i * 256;
        int f = e / 200;
        int m = e - f * 200;
        const float* s = src + (size_t)(bb * F_ + f0 + f) * T_;
        float v;
        if (m < M_ - 1) {
            int tt = 3 * m + 1;
            v = s[tt] + s[tt + 1] + s[tt + 2];
        } else {
            v = s[0] + s[598] + s[599];   // segment 199: t in {0,598,599}
        }
        tile[f][m] = f2bf(v);
    }
    __syncthreads();
    // write out transposed: row m gets 32 consecutive f (64B); lanes g=0..7 x 4 bf16
    #pragma unroll
    for (int it = 0; it < 7; ++it) {
        int m = (t >> 3) + it * 32;
        if (m >= M_) continue;
        int g = (t & 7) * 4;
        ushort4 v;
        v.x = tile[g + 0][m];
        v.y = tile[g + 1][m];
        v.z = tile[g + 2][m];
        v.w = tile[g + 3][m];
        *(ushort4*)(dst + (size_t)(bb * M_ + m) * F_ + f0 + g) = v;
    }
}

// ---------------------------------------------------------------------------
// Row norms from bf16 (B,M,F): one wave per (b,m); 512 bf16 = 16B/lane
// grid: (B_*M_/4, 2), block 256 (4 waves)
// ---------------------------------------------------------------------------
__global__ __launch_bounds__(256)
void norm_kernel(const unsigned short* __restrict__ fa, const unsigned short* __restrict__ fb,
                 float* __restrict__ na, float* __restrict__ nb) {
    const unsigned short* src = (blockIdx.y == 0) ? fa : fb;
    float*                dst = (blockIdx.y == 0) ? na : nb;
    int wave = threadIdx.x >> 6;
    int lane = threadIdx.x & 63;
    int bm = blockIdx.x * 4 + wave;
    const ushort4* p = (const ushort4*)(src + (size_t)bm * F_ + lane * 8);
    ushort4 u0 = p[0], u1 = p[1];
    float acc = 0.f;
    float x;
    x = bf2f(u0.x); acc = fmaf(x, x, acc);
    x = bf2f(u0.y); acc = fmaf(x, x, acc);
    x = bf2f(u0.z); acc = fmaf(x, x, acc);
    x = bf2f(u0.w); acc = fmaf(x, x, acc);
    x = bf2f(u1.x); acc = fmaf(x, x, acc);
    x = bf2f(u1.y); acc = fmaf(x, x, acc);
    x = bf2f(u1.z); acc = fmaf(x, x, acc);
    x = bf2f(u1.w); acc = fmaf(x, x, acc);
    #pragma unroll
    for (int off = 32; off >= 1; off >>= 1)
        acc += __shfl_xor(acc, off, 64);
    if (lane == 0) dst[bm] = sqrtf(acc);
}

// ---------------------------------------------------------------------------
// Batched MFMA GEMM: C[b,m,n] = sum_f fa[b,m,f] * fb[b,n,f]
// 64x64 tile, BK=64, 4 waves (2x2), each wave 32x32 via 2x2 mfma_16x16x32 frags
// ---------------------------------------------------------------------------
#define BK_ 64
__global__ __launch_bounds__(256)
void gemm_kernel(const unsigned short* __restrict__ fa, const unsigned short* __restrict__ fb,
                 float* __restrict__ num) {
    __shared__ unsigned short As[64][88];   // [m][k], pad to 176B rows (~4-way on frag reads)
    __shared__ unsigned short Bs[64][88];   // [n][k]

    int bb = blockIdx.z;
    int m0 = blockIdx.x * 64;
    int n0 = blockIdx.y * 64;
    const unsigned short* A = fa + (size_t)bb * M_ * F_;
    const unsigned short* B = fb + (size_t)bb * M_ * F_;

    int t    = threadIdx.x;
    int lane = t & 63;
    int wid  = t >> 6;           // 0..3
    int wm32 = (wid >> 1) * 32;  // wave m-offset in tile
    int wn32 = (wid & 1) * 32;   // wave n-offset in tile

    int sr = t >> 3;             // staging row 0..31
    int sc = (t & 7) * 8;        // staging col (bf16 index)

    f32x4_t acc[2][2];
    #pragma unroll
    for (int i = 0; i < 2; ++i)
        #pragma unroll
        for (int j = 0; j < 2; ++j)
            acc[i][j] = (f32x4_t)(0.f);

    const uint4 z4 = make_uint4(0, 0, 0, 0);
    for (int k0 = 0; k0 < F_; k0 += BK_) {
        #pragma unroll
        for (int p = 0; p < 2; ++p) {
            int r  = p * 32 + sr;
            int gm = m0 + r, gn = n0 + r;
            uint4 va = z4, vb = z4;
            if (gm < M_) va = *(const uint4*)(A + (size_t)gm * F_ + k0 + sc);
            if (gn < M_) vb = *(const uint4*)(B + (size_t)gn * F_ + k0 + sc);
            *(uint4*)&As[r][sc] = va;
            *(uint4*)&Bs[r][sc] = vb;
        }
        __syncthreads();
        #pragma unroll
        for (int kk = 0; kk < 2; ++kk) {
            int kc = kk * 32 + (lane >> 4) * 8;   // 8 contiguous bf16 per lane
            int rl = lane & 15;
            bf16x8_t a0 = *(const bf16x8_t*)&As[wm32 + rl][kc];
            bf16x8_t a1 = *(const bf16x8_t*)&As[wm32 + 16 + rl][kc];
            bf16x8_t b0 = *(const bf16x8_t*)&Bs[wn32 + rl][kc];
            bf16x8_t b1 = *(const bf16x8_t*)&Bs[wn32 + 16 + rl][kc];
            acc[0][0] = __builtin_amdgcn_mfma_f32_16x16x32_bf16(a0, b0, acc[0][0], 0, 0, 0);
            acc[0][1] = __builtin_amdgcn_mfma_f32_16x16x32_bf16(a0, b1, acc[0][1], 0, 0, 0);
            acc[1][0] = __builtin_amdgcn_mfma_f32_16x16x32_bf16(a1, b0, acc[1][0], 0, 0, 0);
            acc[1][1] = __builtin_amdgcn_mfma_f32_16x16x32_bf16(a1, b1, acc[1][1], 0, 0, 0);
        }
        __syncthreads();
    }

    // C/D layout (m89-verified): col = lane&15, row = (lane>>4)*4 + reg
    float* C = num + (size_t)bb * M_ * M_;
    int r0 = (lane >> 4) * 4;
    int cc = lane & 15;
    #pragma unroll
    for (int i = 0; i < 2; ++i) {
        #pragma unroll
        for (int j = 0; j < 2; ++j) {
            #pragma unroll
            for (int r = 0; r < 4; ++r) {
                int m = m0 + wm32 + i * 16 + r0 + r;
                int n = n0 + wn32 + j * 16 + cc;
                if (m < M_ && n < M_) C[(size_t)m * M_ + n] = acc[i][j][r];
            }
        }
    }
}

// ---------------------------------------------------------------------------
// cosine + log-softmax + diag: one 64-lane wave per (b,m) row
// ---------------------------------------------------------------------------
__global__ __launch_bounds__(64)
void row_softmax_kernel(const float* __restrict__ num,
                        const float* __restrict__ na,
                        const float* __restrict__ nb,
                        float* __restrict__ partial) {
    int bm = blockIdx.x;
    int b  = bm / M_;
    int m  = bm - b * M_;
    int lane = threadIdx.x;
    const float* row = num + (size_t)b * M_ * M_ + (size_t)m * M_;
    const float* nbp = nb + b * M_;
    float nam = na[bm];

    float cosv[4];
    float mx = -INFINITY;
    #pragma unroll
    for (int r = 0; r < 4; ++r) {
        int n = lane + r * 64;
        float c = -INFINITY;
        if (n < M_) {
            float denom = fmaxf(nam * nbp[n], 1e-8f);
            c = row[n] / denom;
        }
        cosv[r] = c;
        mx = fmaxf(mx, c);
    }
    #pragma unroll
    for (int off = 32; off >= 1; off >>= 1)
        mx = fmaxf(mx, __shfl_xor(mx, off, 64));

    float s = 0.f, diag = 0.f;
    #pragma unroll
    for (int r = 0; r < 4; ++r) {
        int n = lane + r * 64;
        if (n < M_) {
            s += __expf(cosv[r] - mx);
            if (n == m) diag = cosv[r];
        }
    }
    #pragma unroll
    for (int off = 32; off >= 1; off >>= 1) {
        s    += __shfl_xor(s, off, 64);
        diag += __shfl_xor(diag, off, 64);
    }
    if (lane == 0) {
        float lse = mx + __logf(s);
        partial[bm] = -(diag - lse) / (float)M_;
    }
}

__global__ __launch_bounds__(256)
void final_reduce_kernel(const float* __restrict__ partial, float* __restrict__ out, int n) {
    __shared__ float sm[256];
    float acc = 0.f;
    for (int i = threadIdx.x; i < n; i += 256) acc += partial[i];
    sm[threadIdx.x] = acc;
    __syncthreads();
    #pragma unroll
    for (int st = 128; st > 0; st >>= 1) {
        if (threadIdx.x < st) sm[threadIdx.x] += sm[threadIdx.x + st];
        __syncthreads();
    }
    if (threadIdx.x == 0) out[0] = sm[0];
}

extern "C" void kernel_launch(void* const* d_in, const int* in_sizes, int n_in,
                              void* d_out, int out_size, void* d_ws, size_t ws_size,
                              hipStream_t stream) {
    // d_in[0] = data_label (int64) -- unused by the loss
    const float* a_in = (const float*)d_in[1];
    const float* b_in = (const float*)d_in[2];

    const size_t merged_elems = (size_t)B_ * M_ * F_;         // 6,553,600
    unsigned short* fa = (unsigned short*)d_ws;               // bf16 (B,M,F)
    unsigned short* fb = fa + merged_elems;
    float* num     = (float*)(fb + merged_elems);             // B*M*M fp32
    float* na      = num + (size_t)B_ * M_ * M_;
    float* nb      = na + B_ * M_;
    float* partial = nb + B_ * M_;                            // B*M

    // 1. merge + transpose + bf16 cast
    merge_t_kernel<<<dim3(B_ * (F_ / 32), 2), 256, 0, stream>>>(a_in, b_in, fa, fb);
    // 2. row norms
    norm_kernel<<<dim3(B_ * M_ / 4, 2), 256, 0, stream>>>(fa, fb, na, nb);
    // 3. batched MFMA GEMM
    gemm_kernel<<<dim3(4, 4, B_), 256, 0, stream>>>(fa, fb, num);
    // 4. cosine + log-softmax diag
    row_softmax_kernel<<<dim3(B_ * M_), 64, 0, stream>>>(num, na, nb, partial);
    // 5. total loss
    final_reduce_kernel<<<1, 256, 0, stream>>>(partial, (float*)d_out, B_ * M_);
}